// Round 1
// baseline (88.019 us; speedup 1.0000x reference)
//
#include <hip/hip_runtime.h>

// GAT block, algebraically collapsed:
//   attention diag[b,f,n] = softmax_n( x[b,:,f,n] . (W @ a2) )[n] * mask[n,n]
//   out[b,h,f,n] = diag[b,f,n] * (sum_c x[b,c,f,n]*W[c,h] + bW[h])
// s1, ab, bW.a2 all cancel inside the row-softmax (constant over the softmax axis).

namespace {
constexpr int B_ = 32, C_ = 3, F_ = 2048, N_ = 25, H_ = 64;
constexpr int TF = 64;               // frames per block tile
constexpr int TPOS = TF * N_;        // 1600 (f,n) positions per tile
constexpr int TVEC = TPOS / 4;       // 400 float4 slots per tile
constexpr int FN = F_ * N_;          // 51200
constexpr int THREADS = 256;
}

__global__ __launch_bounds__(THREADS) void gat_fused(
    const float* __restrict__ x, const float* __restrict__ mask,
    const float* __restrict__ W, const float* __restrict__ bW,
    const float* __restrict__ a2, float* __restrict__ out)
{
  __shared__ float4 x4[3 * TVEC];   // staged x tile: [c][400] float4
  __shared__ float4 d4[TVEC];       // diag-scale per (f,n) position
  __shared__ float Wl[C_ * H_];
  __shared__ float bWl[H_];
  __shared__ float a2l[H_];
  __shared__ float mdl[N_];
  __shared__ float wal[C_];

  const int tid = threadIdx.x;
  const int blk = blockIdx.x;       // 0..1023
  const int b  = blk >> 5;          // F_/TF = 32 tiles per batch
  const int ft = blk & 31;
  const size_t fbase = (size_t)ft * TPOS;   // float offset inside [F*N]

  // --- stage small params ---
  if (tid < C_ * H_) Wl[tid] = W[tid];
  if (tid < H_) { bWl[tid] = bW[tid]; a2l[tid] = a2[tid]; }
  if (tid < N_) mdl[tid] = mask[tid * N_ + tid];

  // --- stage x tile (3 contiguous 1600-float runs, float4) ---
  const float4* xg = (const float4*)x;
  for (int i = tid; i < 3 * TVEC; i += THREADS) {
    int c = i / TVEC;
    int j = i - c * TVEC;
    x4[i] = xg[(((size_t)(b * 3 + c) * FN + fbase) >> 2) + j];
  }
  __syncthreads();

  // --- wa[c] = W[c,:] . a2 ---
  if (tid < C_) {
    float s = 0.f;
    for (int h = 0; h < H_; ++h) s += Wl[tid * H_ + h] * a2l[h];
    wal[tid] = s;
  }
  __syncthreads();

  // --- per-frame 25-way softmax -> d[f][n] ---
  if (tid < TF) {
    const float* xl = (const float*)x4;
    const float wa0 = wal[0], wa1 = wal[1], wa2 = wal[2];
    const int base = tid * N_;
    float s[N_];
    float m = -3.0e38f;
#pragma unroll
    for (int n = 0; n < N_; ++n) {
      float v = fmaf(xl[2 * TPOS + base + n], wa2,
                fmaf(xl[TPOS + base + n], wa1, xl[base + n] * wa0));
      s[n] = v;
      m = fmaxf(m, v);
    }
    float z = 0.f;
#pragma unroll
    for (int n = 0; n < N_; ++n) { s[n] = __expf(s[n] - m); z += s[n]; }
    const float inv = 1.f / z;
    float* dl = (float*)d4;
#pragma unroll
    for (int n = 0; n < N_; ++n) dl[base + n] = s[n] * inv * mdl[n];
  }
  __syncthreads();

  // --- write phase: each thread owns float4 slots {tid, tid+256} of 400 ---
  const bool has2 = (tid + THREADS) < TVEC;   // tid < 144
  const float4 xa0 = x4[tid];
  const float4 xa1 = x4[TVEC + tid];
  const float4 xa2 = x4[2 * TVEC + tid];
  const float4 da  = d4[tid];
  float4 xb0 = {}, xb1 = {}, xb2 = {}, db = {};
  if (has2) {
    xb0 = x4[tid + THREADS];
    xb1 = x4[TVEC + tid + THREADS];
    xb2 = x4[2 * TVEC + tid + THREADS];
    db  = d4[tid + THREADS];
  }

  float4* og = (float4*)out;
  const size_t ob = ((size_t)b * H_ * FN + fbase) >> 2;   // float4 units
  for (int h = 0; h < H_; ++h) {
    const float w0 = Wl[h], w1 = Wl[H_ + h], w2 = Wl[2 * H_ + h], bw = bWl[h];
    const size_t vb = ob + (size_t)h * (FN / 4);
    float4 o;
    o.x = da.x * fmaf(xa2.x, w2, fmaf(xa1.x, w1, fmaf(xa0.x, w0, bw)));
    o.y = da.y * fmaf(xa2.y, w2, fmaf(xa1.y, w1, fmaf(xa0.y, w0, bw)));
    o.z = da.z * fmaf(xa2.z, w2, fmaf(xa1.z, w1, fmaf(xa0.z, w0, bw)));
    o.w = da.w * fmaf(xa2.w, w2, fmaf(xa1.w, w1, fmaf(xa0.w, w0, bw)));
    og[vb + tid] = o;
    if (has2) {
      float4 o2;
      o2.x = db.x * fmaf(xb2.x, w2, fmaf(xb1.x, w1, fmaf(xb0.x, w0, bw)));
      o2.y = db.y * fmaf(xb2.y, w2, fmaf(xb1.y, w1, fmaf(xb0.y, w0, bw)));
      o2.z = db.z * fmaf(xb2.z, w2, fmaf(xb1.z, w1, fmaf(xb0.z, w0, bw)));
      o2.w = db.w * fmaf(xb2.w, w2, fmaf(xb1.w, w1, fmaf(xb0.w, w0, bw)));
      og[vb + tid + THREADS] = o2;
    }
  }
}

extern "C" void kernel_launch(void* const* d_in, const int* in_sizes, int n_in,
                              void* d_out, int out_size, void* d_ws, size_t ws_size,
                              hipStream_t stream) {
  const float* x    = (const float*)d_in[0];  // [B,C,F,N]
  const float* mask = (const float*)d_in[1];  // [N,N]
  const float* W    = (const float*)d_in[2];  // [C,H]
  const float* bW   = (const float*)d_in[3];  // [H]
  // d_in[4] = a1 (cancels in softmax), d_in[6] = ab (cancels)
  const float* a2   = (const float*)d_in[5];  // [H]
  float* out = (float*)d_out;                 // [B,H,F,N]

  dim3 grid(B_ * (F_ / TF));
  dim3 block(THREADS);
  hipLaunchKernelGGL(gat_fused, grid, block, 0, stream, x, mask, W, bW, a2, out);
}